// Round 2
// baseline (897.679 us; speedup 1.0000x reference)
//
#include <hip/hip_runtime.h>
#include <hip/hip_bf16.h>
#include <stdint.h>

// ---------------------------------------------------------------------------
// GraphAttentionLayer: out = softmax(lrelu(s1_i + s2_j)) @ h,  h = x @ W^T
// Round 5:
//  - GEMM: drop the 8-barrier lockstep. Prefetch exactly ONE K-tile ahead
//    (always the other LDS buffer) -> only 1 vmcnt(0)+barrier per K-tile;
//    ds_reads and MFMA overlap via cross-wave drift. ks moved to outer loop
//    in the MFMA cluster (8 independent MFMAs between dependent pairs).
//  - boff: was 16 blocks x 128-deep serial dependent-load chain (latency-
//    bound). Now 64 blocks, 4 k-segments/column in parallel + LDS combine.
//  - pass1/pass2: 8B loads (4 elems/thread), unroll 8, float4 stores.
// ---------------------------------------------------------------------------

typedef float  f32x4  __attribute__((ext_vector_type(4)));
typedef __bf16 bf16x8 __attribute__((ext_vector_type(8)));

#define AS1 __attribute__((address_space(1)))
#define AS3 __attribute__((address_space(3)))

constexpr int NB  = 8192;    // batch rows (i and j)
constexpr int DF  = 4096;    // feature dim
constexpr int CH  = 64;      // sweep chunk length
constexpr int NCH = NB / CH; // 128

constexpr int GK  = DF;      // GEMM K
constexpr int BKK = 64;      // GEMM K-tile
constexpr int NT2 = GK / BKK;

__device__ __forceinline__ uint16_t f2bf_u(float f) {   // RNE fp32 -> bf16
  union { float f; uint32_t u; } x; x.f = f;
  return (uint16_t)((x.u + 0x7FFFu + ((x.u >> 16) & 1u)) >> 16);
}
__device__ __forceinline__ float bfu2f(uint16_t v) {
  union { uint32_t u; float f; } x; x.u = ((uint32_t)v) << 16;
  return x.f;
}

// --------------------------- fp32 -> bf16 convert ---------------------------
__global__ __launch_bounds__(256) void cvt_f32_to_bf16(
    const float* __restrict__ in, uint16_t* __restrict__ out, int n4) {
  int idx = blockIdx.x * 256 + threadIdx.x;
  int stride = gridDim.x * 256;
  for (int i = idx; i < n4; i += stride) {
    float4 v = ((const float4*)in)[i];
    ushort4 o;
    o.x = f2bf_u(v.x); o.y = f2bf_u(v.y); o.z = f2bf_u(v.z); o.w = f2bf_u(v.w);
    ((ushort4*)out)[i] = o;
  }
}

// --------------------------- NT bf16 GEMM: async dbuf -----------------------
// C[M=8192][N=4096] = A[8192][4096] * B[4096][4096]^T, bf16 in/out, fp32 acc.
// LDS per buffer: A tile [256][64] then B tile [256][64] bf16 (32 KB each).
// Swizzle: 16-B granule XOR by (row&7): global source pre-swizzled, LDS dest
// linear (global_load_lds requirement), ds_read address swizzled.

#define STAGE_A(tt, half) do {                                                 \
  const uint16_t* g0_ = Ag + (size_t)((half) * 128) * GK + (size_t)(tt) * BKK; \
  uint32_t d_ = ((uint32_t)((tt) & 1)) * 32768u + (uint32_t)(half) * 8192u +   \
                (uint32_t)wave * 512u;                                         \
  __builtin_amdgcn_global_load_lds((const AS1 void*)g0_,                       \
      (AS3 void*)(lds + d_), 16, 0, 0);                                        \
  __builtin_amdgcn_global_load_lds((const AS1 void*)(g0_ + (size_t)64 * GK),   \
      (AS3 void*)(lds + d_ + 4096u), 16, 0, 0);                                \
} while (0)

#define STAGE_B(tt, half) do {                                                 \
  const uint16_t* g0_ = Bg + (size_t)((half) * 128) * GK + (size_t)(tt) * BKK; \
  uint32_t d_ = ((uint32_t)((tt) & 1)) * 32768u + 16384u +                     \
                (uint32_t)(half) * 8192u + (uint32_t)wave * 512u;              \
  __builtin_amdgcn_global_load_lds((const AS1 void*)g0_,                       \
      (AS3 void*)(lds + d_), 16, 0, 0);                                        \
  __builtin_amdgcn_global_load_lds((const AS1 void*)(g0_ + (size_t)64 * GK),   \
      (AS3 void*)(lds + d_ + 4096u), 16, 0, 0);                                \
} while (0)

#define LDA(mh) do {                                                           \
  _Pragma("unroll") for (int mf = 0; mf < 4; ++mf)                             \
    _Pragma("unroll") for (int ks = 0; ks < 2; ++ks)                           \
      aF[mf][ks] = *(const bf16x8*)(lds + bufo +                               \
          (uint32_t)(wm * 128 + (mh) * 64 + mf * 16 + lr) * 64u +              \
          (uint32_t)((ks * 32 + lg * 8) ^ swl));                               \
} while (0)

#define LDB(nh) do {                                                           \
  _Pragma("unroll") for (int nf = 0; nf < 2; ++nf)                             \
    _Pragma("unroll") for (int ks = 0; ks < 2; ++ks)                           \
      bF[nf][ks] = *(const bf16x8*)(lds + bufo + 16384u +                      \
          (uint32_t)(wn * 64 + (nh) * 32 + nf * 16 + lr) * 64u +               \
          (uint32_t)((ks * 32 + lg * 8) ^ swl));                               \
} while (0)

// ks OUTER: 8 independent MFMAs, then the 8 dependent partners (dep distance 8)
#define MMA(mh, nh) do {                                                       \
  _Pragma("unroll") for (int ks = 0; ks < 2; ++ks)                             \
    _Pragma("unroll") for (int mf = 0; mf < 4; ++mf)                           \
      _Pragma("unroll") for (int nf = 0; nf < 2; ++nf)                         \
        acc[(mh) * 4 + mf][(nh) * 2 + nf] =                                    \
            __builtin_amdgcn_mfma_f32_16x16x32_bf16(aF[mf][ks], bF[nf][ks],    \
                acc[(mh) * 4 + mf][(nh) * 2 + nf], 0, 0, 0);                   \
} while (0)

__global__ __launch_bounds__(512, 2) void gemm_nt_async(
    const uint16_t* __restrict__ A, const uint16_t* __restrict__ B,
    uint16_t* __restrict__ C) {
  __shared__ uint16_t lds[65536];   // 128 KiB: [buf][A|B][256*64]

  const int tid  = threadIdx.x;
  const int wave = tid >> 6;
  const int lane = tid & 63;
  const int lr   = lane & 15;
  const int lg   = lane >> 4;        // 0..3
  const int wm   = wave >> 2;        // 0..1  (M half)
  const int wn   = wave & 3;         // 0..3  (N quarter)
  const int swl  = (lr & 7) << 3;    // read-side XOR swizzle (elements)

  // XCD-aware bijective swizzle over 512 blocks (512 % 8 == 0)
  const int bid = blockIdx.x;
  const int swz = (bid & 7) * 64 + (bid >> 3);
  const int bx  = swz & 15;          // N tile (16)
  const int by  = swz >> 4;          // M tile (32)
  const int rowBase = by * 256;
  const int colBase = bx * 256;

  // stage source: thread t covers LDS row sr, 16-B chunk (t&7); source chunk
  // is pre-swizzled so that linear LDS dest + swizzled read = identity.
  const int sr  = tid >> 3;                    // 0..63
  const int sch = (tid & 7) ^ (sr & 7);
  const uint16_t* Ag = A + (size_t)(rowBase + sr) * GK + sch * 8;
  const uint16_t* Bg = B + (size_t)(colBase + sr) * GK + sch * 8;

  f32x4 acc[8][4];
#pragma unroll
  for (int mf = 0; mf < 8; ++mf)
#pragma unroll
    for (int nf = 0; nf < 4; ++nf) acc[mf][nf] = (f32x4){0.f, 0.f, 0.f, 0.f};

  // prologue: stage tile 0 -> buf0, wait, sync
  STAGE_A(0, 0);
  STAGE_A(0, 1);
  STAGE_B(0, 0);
  STAGE_B(0, 1);
  asm volatile("s_waitcnt vmcnt(0)" ::: "memory");
  __builtin_amdgcn_s_barrier();

  bf16x8 aF[4][2], bF[2][2];

  for (int t = 0; t < NT2; ++t) {
    const uint32_t bufo = ((uint32_t)(t & 1)) * 32768u;

    // prefetch next tile -> OTHER buffer (never touches buffer being read)
    if (t + 1 < NT2) {
      STAGE_A(t + 1, 0);
      STAGE_A(t + 1, 1);
      STAGE_B(t + 1, 0);
      STAGE_B(t + 1, 1);
    }

    // quadrant sweep; compiler inserts fine-grained lgkmcnt waits, 2 waves/SIMD
    // drift to overlap LDS reads with the other wave's MFMA cluster.
    LDA(0); LDB(0);
    MMA(0, 0);
    LDB(1);
    MMA(0, 1);
    LDA(1);
    MMA(1, 1);
    LDB(0);          // re-read B-half0 (cheaper than +16 live VGPRs)
    MMA(1, 0);

    if (t + 1 < NT2) {
      asm volatile("s_waitcnt vmcnt(0)" ::: "memory");  // issued at tile top ->
      __builtin_amdgcn_s_barrier();                     // latency fully hidden
    }
  }

  // epilogue: C/D layout col = lane&15, row = (lane>>4)*4 + reg
  const int r0 = rowBase + wm * 128 + lg * 4;
  const int c0 = colBase + wn * 64 + lr;
#pragma unroll
  for (int mf = 0; mf < 8; ++mf)
#pragma unroll
    for (int nf = 0; nf < 4; ++nf)
#pragma unroll
      for (int e = 0; e < 4; ++e)
        C[(size_t)(r0 + mf * 16 + e) * (size_t)DF + (c0 + nf * 16)] =
            f2bf_u(acc[mf][nf][e]);
}

// --------------------------- s1/s2: h @ a1, h @ a2 --------------------------
__global__ __launch_bounds__(256) void s12_kernel(
    const uint16_t* __restrict__ h, const float* __restrict__ a,
    float* __restrict__ s1, float* __restrict__ s2) {
  const int wave = threadIdx.x >> 6, lane = threadIdx.x & 63;
  const int row = blockIdx.x * 4 + wave;
  const uint32_t* hr = (const uint32_t*)(h + (size_t)row * DF);
  float d1 = 0.f, d2 = 0.f;
#pragma unroll 4
  for (int it = 0; it < DF / 128; it++) {
    int u = it * 64 + lane;
    uint32_t hv = hr[u];
    float lo = bfu2f((uint16_t)hv), hi = bfu2f((uint16_t)(hv >> 16));
    int k = 2 * u;
    d1 += a[k] * lo + a[k + 1] * hi;
    d2 += a[DF + k] * lo + a[DF + k + 1] * hi;
  }
  for (int off = 32; off > 0; off >>= 1) {
    d1 += __shfl_down(d1, off, 64);
    d2 += __shfl_down(d2, off, 64);
  }
  if (lane == 0) { s1[row] = d1; s2[row] = d2; }
}

// --------------------------- rank sort of s2 (descending) -------------------
__global__ __launch_bounds__(256) void rank_kernel(
    const float* __restrict__ s2, int* __restrict__ pi,
    float* __restrict__ s2sorted) {
  __shared__ float ld[NB];
  for (int idx = threadIdx.x; idx < NB; idx += 256) ld[idx] = s2[idx];
  __syncthreads();
  const int j = blockIdx.x * 256 + threadIdx.x;
  const float v = ld[j];
  int cnt = 0;
  for (int q = 0; q < NB / 4; q++) {
    float4 u = ((const float4*)ld)[q];
    int jj = q * 4;
    cnt += (u.x > v) || (u.x == v && (jj + 0) < j);
    cnt += (u.y > v) || (u.y == v && (jj + 1) < j);
    cnt += (u.z > v) || (u.z == v && (jj + 2) < j);
    cnt += (u.w > v) || (u.w == v && (jj + 3) < j);
  }
  pi[cnt] = j;
  s2sorted[cnt] = v;
}

// --------------------------- c_i = #{j : s2_j > -s1_i} ----------------------
__global__ __launch_bounds__(256) void count_kernel(
    const float* __restrict__ s1, const float* __restrict__ s2,
    int* __restrict__ ci) {
  __shared__ float ld[NB];
  for (int idx = threadIdx.x; idx < NB; idx += 256) ld[idx] = s2[idx];
  __syncthreads();
  const int i = blockIdx.x * 256 + threadIdx.x;
  const float thr = -s1[i];
  int cnt = 0;
  for (int q = 0; q < NB / 4; q++) {
    float4 u = ((const float4*)ld)[q];
    cnt += (u.x > thr) + (u.y > thr) + (u.z > thr) + (u.w > thr);
  }
  ci[i] = cnt;
}

// --------------------------- scalar weights + prefix sums -------------------
__global__ __launch_bounds__(256) void scan_kernel(
    const float* __restrict__ s2sorted, float* __restrict__ Sb,
    float* __restrict__ Sc, float* __restrict__ wbg, float* __restrict__ wcg) {
  __shared__ float pb[256], pc[256];
  const int t = threadIdx.x;
  float sb = 0.f, sc = 0.f;
  for (int c = t * 32; c < t * 32 + 32; c++) {
    float s = s2sorted[c];
    float wb = __expf(0.2f * s), wc = __expf(s);
    wbg[c] = wb; wcg[c] = wc;
    sb += wb; sc += wc;
  }
  pb[t] = sb; pc[t] = sc;
  __syncthreads();
  if (t == 0) {
    float rb = 0.f, rc = 0.f;
    for (int q = 0; q < 256; q++) {
      float tb = pb[q], tc = pc[q];
      pb[q] = rb; pc[q] = rc;
      rb += tb; rc += tc;
    }
    Sb[0] = 0.f; Sc[0] = 0.f;
    Sb[NB] = rb; Sc[NB] = rc;
  }
  __syncthreads();
  float rb = pb[t], rc = pc[t];
  for (int c = t * 32; c < t * 32 + 32; c++) {
    rb += wbg[c]; rc += wcg[c];
    if (c + 1 < NB) { Sb[c + 1] = rb; Sc[c + 1] = rc; }
  }
}

// --------------------------- bucket machinery -------------------------------
__global__ __launch_bounds__(256) void zero_hist(int* __restrict__ hist) {
  int t = blockIdx.x * 256 + threadIdx.x;
  if (t <= NB) hist[t] = 0;
}

// per-i scalars f1,f2 and histogram of boundary buckets (bucket = c_i)
__global__ __launch_bounds__(256) void finalize_kernel(
    const float* __restrict__ s1, const int* __restrict__ ci,
    const float* __restrict__ Sb, const float* __restrict__ Sc,
    float* __restrict__ f1, float* __restrict__ f2, int* __restrict__ hist) {
  const int i = blockIdx.x * 256 + threadIdx.x;
  const float s1i = s1[i];
  const int c = ci[i];
  const float q1 = __expf(0.2f * s1i), q2 = __expf(s1i);
  const float l = q1 * (Sb[NB] - Sb[c]) + q2 * Sc[c];
  f1[i] = q1 / l;
  f2[i] = q2 / l;
  atomicAdd(&hist[c], 1);
}

// exclusive scan of hist[0..NB] -> istart[0..NB+1]; cursor = copy
__global__ __launch_bounds__(256) void bucket_scan(
    const int* __restrict__ hist, int* __restrict__ istart,
    int* __restrict__ cursor) {
  __shared__ int ps[256];
  const int t = threadIdx.x;
  const int lo = t * 33;
  const int hi = min(lo + 33, NB + 1);
  int s = 0;
  for (int b = lo; b < hi; b++) s += hist[b];
  ps[t] = s;
  __syncthreads();
  if (t == 0) {
    int r = 0;
    for (int q = 0; q < 256; q++) { int v = ps[q]; ps[q] = r; r += v; }
  }
  __syncthreads();
  int r = ps[t];
  for (int b = lo; b < hi; b++) { istart[b] = r; cursor[b] = r; r += hist[b]; }
  if (t == 255) istart[NB + 1] = r;
}

__global__ __launch_bounds__(256) void scatter_kernel(
    const int* __restrict__ ci, int* __restrict__ cursor,
    int* __restrict__ ilist) {
  const int i = blockIdx.x * 256 + threadIdx.x;
  const int b = ci[i];
  const int pos = atomicAdd(&cursor[b], 1);
  ilist[pos] = i;
}

// --------------------------- pass1: chunk totals ----------------------------
// 4 elems/thread (uint2 = 8B loads), unroll 8 -> deep load pipeline.
__global__ __launch_bounds__(256) void pass1_kernel(
    const uint16_t* __restrict__ h, const int* __restrict__ pi,
    const float* __restrict__ wbg, const float* __restrict__ wcg,
    float* __restrict__ Bct, float* __restrict__ Cct) {
  __shared__ int   pj[CH];
  __shared__ float wb[CH], wc[CH];
  const int t  = threadIdx.x;
  const int cb = blockIdx.x;
  const int k  = blockIdx.y;
  if (t < CH) {
    int g = k * CH + t;
    pj[t] = pi[g]; wb[t] = wbg[g]; wc[t] = wcg[g];
  }
  __syncthreads();
  const int n0 = cb * 1024 + t * 4;
  float b0 = 0.f, b1 = 0.f, b2 = 0.f, b3 = 0.f;
  float c0 = 0.f, c1 = 0.f, c2 = 0.f, c3 = 0.f;
#pragma unroll 8
  for (int c = 0; c < CH; c++) {
    uint2 hv = *(const uint2*)(h + (size_t)pj[c] * DF + n0);
    float h0 = bfu2f((uint16_t)hv.x), h1 = bfu2f((uint16_t)(hv.x >> 16));
    float h2 = bfu2f((uint16_t)hv.y), h3 = bfu2f((uint16_t)(hv.y >> 16));
    float vb = wb[c], vc = wc[c];
    b0 += vb * h0; b1 += vb * h1; b2 += vb * h2; b3 += vb * h3;
    c0 += vc * h0; c1 += vc * h1; c2 += vc * h2; c3 += vc * h3;
  }
  *(float4*)(Bct + (size_t)k * DF + n0) = make_float4(b0, b1, b2, b3);
  *(float4*)(Cct + (size_t)k * DF + n0) = make_float4(c0, c1, c2, c3);
}

// --------------------------- chunk offset scan (per column) -----------------
// 64 blocks x 256 threads: 4 k-segments per column in parallel, LDS combine.
__global__ __launch_bounds__(256) void boff_kernel(
    const float* __restrict__ Bct, const float* __restrict__ Cct,
    float* __restrict__ Boff, float* __restrict__ Coff) {
  __shared__ float sB[4][64], sC[4][64];
  const int t   = threadIdx.x;
  const int cl  = t & 63;
  const int seg = t >> 6;                    // 0..3 (32 chunks each)
  const int col = blockIdx.x * 64 + cl;
  float sb = 0.f, sc = 0.f;
#pragma unroll 8
  for (int u = 0; u < NCH / 4; u++) {
    int kk = seg * (NCH / 4) + u;
    sb += Bct[(size_t)kk * DF + col];
    sc += Cct[(size_t)kk * DF + col];
  }
  sB[seg][cl] = sb; sC[seg][cl] = sc;
  __syncthreads();
  float rb = 0.f, rc = 0.f;
#pragma unroll
  for (int s = 0; s < 3; s++)
    if (s < seg) { rb += sB[s][cl]; rc += sC[s][cl]; }
#pragma unroll 4
  for (int u = 0; u < NCH / 4; u++) {
    int kk = seg * (NCH / 4) + u;
    Boff[(size_t)kk * DF + col] = rb;
    Coff[(size_t)kk * DF + col] = rc;
    rb += Bct[(size_t)kk * DF + col];
    rc += Cct[(size_t)kk * DF + col];
  }
  if (seg == 3) {
    Boff[(size_t)NCH * DF + col] = rb;      // = A_n
    Coff[(size_t)NCH * DF + col] = rc;
  }
}

// --------------------------- pass2: sweep + direct emission -----------------
__global__ __launch_bounds__(256) void pass2_kernel(
    const uint16_t* __restrict__ h, const int* __restrict__ pi,
    const float* __restrict__ wbg, const float* __restrict__ wcg,
    const float* __restrict__ Boff, const float* __restrict__ Coff,
    const int* __restrict__ istart, const int* __restrict__ ilist,
    const float* __restrict__ f1, const float* __restrict__ f2,
    float* __restrict__ out) {
  __shared__ int   pj[CH];
  __shared__ float wb[CH], wc[CH];
  __shared__ int   se[CH + 2];
  const int t  = threadIdx.x;
  const int cb = blockIdx.x;
  const int k  = blockIdx.y;
  if (t < CH) {
    int g = k * CH + t;
    pj[t] = pi[g]; wb[t] = wbg[g]; wc[t] = wcg[g];
  }
  if (t < CH + 2) se[t] = istart[k * CH + t];
  __syncthreads();
  const int n0 = cb * 1024 + t * 4;
  const float4 An = *(const float4*)(Boff + (size_t)NCH * DF + n0);
  const float4 Bo = *(const float4*)(Boff + (size_t)k * DF + n0);
  const float4 Co = *(const float4*)(Coff + (size_t)k * DF + n0);
  float b0 = Bo.x, b1 = Bo.y, b2 = Bo.z, b3 = Bo.w;
  float c0 = Co.x, c1 = Co.y, c2 = Co.z, c3 = Co.w;

  if (k == 0) {   // bucket 0: boundary before any j (c_i == 0)
    for (int idx = se[0]; idx < se[1]; idx++) {
      const int i = ilist[idx];
      const float fa = f1[i];
      *(float4*)(out + (size_t)i * DF + n0) =
          make_float4(fa * An.x, fa * An.y, fa * An.z, fa * An.w);
    }
  }
  for (int c = 0; c < CH; c++) {
    uint2 hv = *(const uint2*)(h + (size_t)pj[c] * DF + n0);
    float h0 = bfu2f((uint16_t)hv.x), h1 = bfu2f((uint16_t)(hv.x >> 16));
    float h2 = bfu2f((uint16_t)hv.y), h3 = bfu2f((uint16_t)(hv.y >> 16));
    float vb = wb[c], vc = wc[c];
    b0 += vb * h0; b1 += vb * h1; b2 += vb * h2; b3 += vb * h3;
    c0 += vc * h0; c1 += vc * h1; c2 += vc * h2; c3 += vc * h3;
    const int e0 = se[c + 1], e1 = se[c + 2];
    for (int idx = e0; idx < e1; idx++) {
      const int i = ilist[idx];
      const float fa = f1[i], fb = f2[i];
      *(float4*)(out + (size_t)i * DF + n0) = make_float4(
          fa * (An.x - b0) + fb * c0, fa * (An.y - b1) + fb * c1,
          fa * (An.z - b2) + fb * c2, fa * (An.w - b3) + fb * c3);
    }
  }
}

// ---------------------------------------------------------------------------
extern "C" void kernel_launch(void* const* d_in, const int* in_sizes, int n_in,
                              void* d_out, int out_size, void* d_ws, size_t ws_size,
                              hipStream_t stream) {
  const float* x = (const float*)d_in[0];   // [8192][4096] fp32
  const float* W = (const float*)d_in[1];   // [4096][4096] fp32
  const float* a = (const float*)d_in[2];   // [8192] fp32
  float* out = (float*)d_out;               // [8192][4096] fp32

  char* ws = (char*)d_ws;
  uint16_t* h = (uint16_t*)ws;                 // 64 MB
  char* sm = ws + 67108864;
  float* s1       = (float*)(sm);
  float* s2       = (float*)(sm + 65536);
  float* s2sorted = (float*)(sm + 131072);
  int*   pi       = (int*)  (sm + 196608);
  int*   ci       = (int*)  (sm + 262144);
  float* Sb       = (float*)(sm + 327680);     // NB+1 floats
  float* Sc       = (float*)(sm + 393216);
  float* wbg      = (float*)(sm + 458752);
  float* wcg      = (float*)(sm + 524288);
  float* f1       = (float*)(sm + 589824);
  float* f2       = (float*)(sm + 655360);
  int*   hist     = (int*)  (sm + 720896);     // NB+1 ints
  int*   istart   = (int*)  (sm + 786432);     // NB+2 ints
  int*   cursor   = (int*)  (sm + 851968);     // NB+1 ints
  int*   ilist    = (int*)  (sm + 917504);     // NB ints
  float* Bct      = (float*)(sm + 1048576);    // NCH*DF*4 = 2 MB
  float* Cct      = (float*)(sm + 3145728);    // 2 MB
  float* Boff     = (float*)(sm + 5242880);    // (NCH+1)*DF*4 ~ 2.02 MB
  float* Coff     = (float*)(sm + 7602176);    // ~2.02 MB (ends sm+9.96MB)
  char* base2 = ws + 67108864 + 10485760;      // staging (dead after gemm)
  uint16_t* xb = (uint16_t*)base2;             // 64 MB
  uint16_t* Wb = (uint16_t*)(base2 + 67108864);// 32 MB  (total ws ~169 MB)

  cvt_f32_to_bf16<<<1024, 256, 0, stream>>>(x, xb, (NB * DF) / 4);
  cvt_f32_to_bf16<<<1024, 256, 0, stream>>>(W, Wb, (DF * DF) / 4);

  // GEMM1: h[i][o] = sum_k x[i][k] W[o][k]   (M=8192, N=4096, K=4096)
  gemm_nt_async<<<(NB / 256) * (DF / 256), 512, 0, stream>>>(xb, Wb, h);

  zero_hist<<<33, 256, 0, stream>>>(hist);
  s12_kernel<<<NB / 4, 256, 0, stream>>>(h, a, s1, s2);
  rank_kernel<<<NB / 256, 256, 0, stream>>>(s2, pi, s2sorted);
  count_kernel<<<NB / 256, 256, 0, stream>>>(s1, s2, ci);
  scan_kernel<<<1, 256, 0, stream>>>(s2sorted, Sb, Sc, wbg, wcg);
  finalize_kernel<<<NB / 256, 256, 0, stream>>>(s1, ci, Sb, Sc, f1, f2, hist);
  bucket_scan<<<1, 256, 0, stream>>>(hist, istart, cursor);
  scatter_kernel<<<NB / 256, 256, 0, stream>>>(ci, cursor, ilist);

  pass1_kernel<<<dim3(DF / 1024, NCH), 256, 0, stream>>>(h, pi, wbg, wcg, Bct, Cct);
  boff_kernel<<<DF / 64, 256, 0, stream>>>(Bct, Cct, Boff, Coff);
  pass2_kernel<<<dim3(DF / 1024, NCH), 256, 0, stream>>>(
      h, pi, wbg, wcg, Boff, Coff, istart, ilist, f1, f2, out);
}

// Round 3
// 723.776 us; speedup vs baseline: 1.2403x; 1.2403x over previous
//
#include <hip/hip_runtime.h>
#include <hip/hip_bf16.h>
#include <stdint.h>

// ---------------------------------------------------------------------------
// GraphAttentionLayer: out = softmax(lrelu(s1_i + s2_j)) @ h,  h = x @ W^T
// Round 6: launch-count + serial-scan attack (GEMM K-loop frozen at R5).
//  - s12 fused into GEMM epilogue (fp32 acc partial dots + shfl + atomicAdd)
//  - rank+count merged, 4-way j-split (128 blocks, 512 iters/thread)
//  - scan+finalize+bucket_scan merged into one single-block kernel w/ LDS hist
//  - scatter folded into pass1
//  13 launches -> 8.
// ---------------------------------------------------------------------------

typedef float  f32x4  __attribute__((ext_vector_type(4)));
typedef __bf16 bf16x8 __attribute__((ext_vector_type(8)));

#define AS1 __attribute__((address_space(1)))
#define AS3 __attribute__((address_space(3)))

constexpr int NB  = 8192;    // batch rows (i and j)
constexpr int DF  = 4096;    // feature dim
constexpr int CH  = 64;      // sweep chunk length
constexpr int NCH = NB / CH; // 128

constexpr int GK  = DF;      // GEMM K
constexpr int BKK = 64;      // GEMM K-tile
constexpr int NT2 = GK / BKK;

__device__ __forceinline__ uint16_t f2bf_u(float f) {   // RNE fp32 -> bf16
  union { float f; uint32_t u; } x; x.f = f;
  return (uint16_t)((x.u + 0x7FFFu + ((x.u >> 16) & 1u)) >> 16);
}
__device__ __forceinline__ float bfu2f(uint16_t v) {
  union { uint32_t u; float f; } x; x.u = ((uint32_t)v) << 16;
  return x.f;
}

// --------------------------- fp32 -> bf16 convert (+opt zero) ---------------
__global__ __launch_bounds__(256) void cvt_f32_to_bf16(
    const float* __restrict__ in, uint16_t* __restrict__ out, int n4,
    float* __restrict__ z1, float* __restrict__ z2, int zn) {
  int idx = blockIdx.x * 256 + threadIdx.x;
  int stride = gridDim.x * 256;
  if (z1) {
    for (int g = idx; g < zn; g += stride) { z1[g] = 0.f; z2[g] = 0.f; }
  }
  for (int i = idx; i < n4; i += stride) {
    float4 v = ((const float4*)in)[i];
    ushort4 o;
    o.x = f2bf_u(v.x); o.y = f2bf_u(v.y); o.z = f2bf_u(v.z); o.w = f2bf_u(v.w);
    ((ushort4*)out)[i] = o;
  }
}

// --------------------------- NT bf16 GEMM: async dbuf + fused s12 -----------
// C[M=8192][N=4096] = A[8192][4096] * B[4096][4096]^T, bf16 in/out, fp32 acc.
// Epilogue additionally accumulates s1[i]=h_i.a1, s2[i]=h_i.a2 from fp32 acc.

#define STAGE_A(tt, half) do {                                                 \
  const uint16_t* g0_ = Ag + (size_t)((half) * 128) * GK + (size_t)(tt) * BKK; \
  uint32_t d_ = ((uint32_t)((tt) & 1)) * 32768u + (uint32_t)(half) * 8192u +   \
                (uint32_t)wave * 512u;                                         \
  __builtin_amdgcn_global_load_lds((const AS1 void*)g0_,                       \
      (AS3 void*)(lds + d_), 16, 0, 0);                                        \
  __builtin_amdgcn_global_load_lds((const AS1 void*)(g0_ + (size_t)64 * GK),   \
      (AS3 void*)(lds + d_ + 4096u), 16, 0, 0);                                \
} while (0)

#define STAGE_B(tt, half) do {                                                 \
  const uint16_t* g0_ = Bg + (size_t)((half) * 128) * GK + (size_t)(tt) * BKK; \
  uint32_t d_ = ((uint32_t)((tt) & 1)) * 32768u + 16384u +                     \
                (uint32_t)(half) * 8192u + (uint32_t)wave * 512u;              \
  __builtin_amdgcn_global_load_lds((const AS1 void*)g0_,                       \
      (AS3 void*)(lds + d_), 16, 0, 0);                                        \
  __builtin_amdgcn_global_load_lds((const AS1 void*)(g0_ + (size_t)64 * GK),   \
      (AS3 void*)(lds + d_ + 4096u), 16, 0, 0);                                \
} while (0)

#define LDA(mh) do {                                                           \
  _Pragma("unroll") for (int mf = 0; mf < 4; ++mf)                             \
    _Pragma("unroll") for (int ks = 0; ks < 2; ++ks)                           \
      aF[mf][ks] = *(const bf16x8*)(lds + bufo +                               \
          (uint32_t)(wm * 128 + (mh) * 64 + mf * 16 + lr) * 64u +              \
          (uint32_t)((ks * 32 + lg * 8) ^ swl));                               \
} while (0)

#define LDB(nh) do {                                                           \
  _Pragma("unroll") for (int nf = 0; nf < 2; ++nf)                             \
    _Pragma("unroll") for (int ks = 0; ks < 2; ++ks)                           \
      bF[nf][ks] = *(const bf16x8*)(lds + bufo + 16384u +                      \
          (uint32_t)(wn * 64 + (nh) * 32 + nf * 16 + lr) * 64u +               \
          (uint32_t)((ks * 32 + lg * 8) ^ swl));                               \
} while (0)

#define MMA(mh, nh) do {                                                       \
  _Pragma("unroll") for (int ks = 0; ks < 2; ++ks)                             \
    _Pragma("unroll") for (int mf = 0; mf < 4; ++mf)                           \
      _Pragma("unroll") for (int nf = 0; nf < 2; ++nf)                         \
        acc[(mh) * 4 + mf][(nh) * 2 + nf] =                                    \
            __builtin_amdgcn_mfma_f32_16x16x32_bf16(aF[mf][ks], bF[nf][ks],    \
                acc[(mh) * 4 + mf][(nh) * 2 + nf], 0, 0, 0);                   \
} while (0)

__global__ __launch_bounds__(512, 2) void gemm_nt_async(
    const uint16_t* __restrict__ A, const uint16_t* __restrict__ B,
    uint16_t* __restrict__ C, const float* __restrict__ a,
    float* __restrict__ s1g, float* __restrict__ s2g) {
  __shared__ uint16_t lds[65536];   // 128 KiB: [buf][A|B][256*64]

  const int tid  = threadIdx.x;
  const int wave = tid >> 6;
  const int lane = tid & 63;
  const int lr   = lane & 15;
  const int lg   = lane >> 4;        // 0..3
  const int wm   = wave >> 2;        // 0..1  (M half)
  const int wn   = wave & 3;         // 0..3  (N quarter)
  const int swl  = (lr & 7) << 3;    // read-side XOR swizzle (elements)

  // XCD-aware bijective swizzle over 512 blocks (512 % 8 == 0)
  const int bid = blockIdx.x;
  const int swz = (bid & 7) * 64 + (bid >> 3);
  const int bx  = swz & 15;          // N tile (16)
  const int by  = swz >> 4;          // M tile (32)
  const int rowBase = by * 256;
  const int colBase = bx * 256;

  // stage source: thread t covers LDS row sr, 16-B chunk (t&7); source chunk
  // is pre-swizzled so that linear LDS dest + swizzled read = identity.
  const int sr  = tid >> 3;                    // 0..63
  const int sch = (tid & 7) ^ (sr & 7);
  const uint16_t* Ag = A + (size_t)(rowBase + sr) * GK + sch * 8;
  const uint16_t* Bg = B + (size_t)(colBase + sr) * GK + sch * 8;

  f32x4 acc[8][4];
#pragma unroll
  for (int mf = 0; mf < 8; ++mf)
#pragma unroll
    for (int nf = 0; nf < 4; ++nf) acc[mf][nf] = (f32x4){0.f, 0.f, 0.f, 0.f};

  // prologue: stage tile 0 -> buf0, wait, sync
  STAGE_A(0, 0);
  STAGE_A(0, 1);
  STAGE_B(0, 0);
  STAGE_B(0, 1);
  asm volatile("s_waitcnt vmcnt(0)" ::: "memory");
  __builtin_amdgcn_s_barrier();

  bf16x8 aF[4][2], bF[2][2];

  for (int t = 0; t < NT2; ++t) {
    const uint32_t bufo = ((uint32_t)(t & 1)) * 32768u;

    // prefetch next tile -> OTHER buffer (never touches buffer being read)
    if (t + 1 < NT2) {
      STAGE_A(t + 1, 0);
      STAGE_A(t + 1, 1);
      STAGE_B(t + 1, 0);
      STAGE_B(t + 1, 1);
    }

    LDA(0); LDB(0);
    MMA(0, 0);
    LDB(1);
    MMA(0, 1);
    LDA(1);
    MMA(1, 1);
    LDB(0);          // re-read B-half0 (cheaper than +16 live VGPRs)
    MMA(1, 0);

    if (t + 1 < NT2) {
      asm volatile("s_waitcnt vmcnt(0)" ::: "memory");
      __builtin_amdgcn_s_barrier();
    }
  }

  // epilogue: C/D layout col = lane&15, row = (lane>>4)*4 + reg
  const int r0 = rowBase + wm * 128 + lg * 4;
  const int c0 = colBase + wn * 64 + lr;
#pragma unroll
  for (int mf = 0; mf < 8; ++mf)
#pragma unroll
    for (int nf = 0; nf < 4; ++nf)
#pragma unroll
      for (int e = 0; e < 4; ++e)
        C[(size_t)(r0 + mf * 16 + e) * (size_t)DF + (c0 + nf * 16)] =
            f2bf_u(acc[mf][nf][e]);

  // ---- fused s12: partial dots of this block's columns with a1/a2 ----
  float a1v[4], a2v[4];
#pragma unroll
  for (int nf = 0; nf < 4; ++nf) {
    int col = c0 + nf * 16;
    a1v[nf] = a[col];
    a2v[nf] = a[DF + col];
  }
#pragma unroll
  for (int mf = 0; mf < 8; ++mf) {
#pragma unroll
    for (int e = 0; e < 4; ++e) {
      float p1 = 0.f, p2 = 0.f;
#pragma unroll
      for (int nf = 0; nf < 4; ++nf) {
        float hv = acc[mf][nf][e];
        p1 += hv * a1v[nf];
        p2 += hv * a2v[nf];
      }
      p1 += __shfl_xor(p1, 1, 64); p1 += __shfl_xor(p1, 2, 64);
      p1 += __shfl_xor(p1, 4, 64); p1 += __shfl_xor(p1, 8, 64);
      p2 += __shfl_xor(p2, 1, 64); p2 += __shfl_xor(p2, 2, 64);
      p2 += __shfl_xor(p2, 4, 64); p2 += __shfl_xor(p2, 8, 64);
      if (lr == 0) {
        int row = r0 + mf * 16 + e;
        atomicAdd(&s1g[row], p1);
        atomicAdd(&s2g[row], p2);
      }
    }
  }
}

// --------------------------- rank + count, 4-way j-split --------------------
// thread group of 4 handles one index i: rank of s2[i] (desc, tie by idx) and
// c_i = #{j : s2_j > -s1_i}. 128 blocks x 64 i's.
__global__ __launch_bounds__(256) void rankcount_kernel(
    const float* __restrict__ s1, const float* __restrict__ s2,
    int* __restrict__ pi, float* __restrict__ s2sorted, int* __restrict__ ci) {
  __shared__ float ld[NB];
  const int t = threadIdx.x;
  for (int idx = t; idx < NB; idx += 256) ld[idx] = s2[idx];
  __syncthreads();
  const int i    = blockIdx.x * 64 + (t >> 2);
  const int part = t & 3;
  const float v   = ld[i];
  const float thr = -s1[i];
  int cr = 0, cc = 0;
  const int q0 = part * (NB / 16);   // float4 units, NB/16 = 512 per part
  for (int q = q0; q < q0 + NB / 16; q++) {
    float4 u = ((const float4*)ld)[q];
    int jj = q * 4;
    cr += (u.x > v) || (u.x == v && (jj + 0) < i);
    cr += (u.y > v) || (u.y == v && (jj + 1) < i);
    cr += (u.z > v) || (u.z == v && (jj + 2) < i);
    cr += (u.w > v) || (u.w == v && (jj + 3) < i);
    cc += (u.x > thr) + (u.y > thr) + (u.z > thr) + (u.w > thr);
  }
  cr += __shfl_xor(cr, 1, 64); cr += __shfl_xor(cr, 2, 64);
  cc += __shfl_xor(cc, 1, 64); cc += __shfl_xor(cc, 2, 64);
  if (part == 0) {
    pi[cr] = i;
    s2sorted[cr] = v;
    ci[i] = cc;
  }
}

// --------------------------- mega: scan + finalize + bucket_scan ------------
// single block; histogram lives in LDS (atomicAdd shared), no global hist.
__global__ __launch_bounds__(256) void mega_kernel(
    const float* __restrict__ s2sorted, float* __restrict__ Sb,
    float* __restrict__ Sc, float* __restrict__ wbg, float* __restrict__ wcg,
    const float* __restrict__ s1, const int* __restrict__ ci,
    float* __restrict__ f1, float* __restrict__ f2,
    int* __restrict__ istart, int* __restrict__ cursor) {
  __shared__ float pb[256], pc[256];
  __shared__ int   histL[NB + 1];
  __shared__ int   ps[256];
  const int t = threadIdx.x;
  for (int g = t; g <= NB; g += 256) histL[g] = 0;

  // ---- scan: weights + prefix sums of exp(0.2 s2) / exp(s2) (sorted) ----
  float sb = 0.f, sc = 0.f;
  for (int c = t * 32; c < t * 32 + 32; c++) {
    float s = s2sorted[c];
    float wb = __expf(0.2f * s), wc = __expf(s);
    wbg[c] = wb; wcg[c] = wc;
    sb += wb; sc += wc;
  }
  pb[t] = sb; pc[t] = sc;
  __syncthreads();
  if (t == 0) {
    float rb = 0.f, rc = 0.f;
    for (int q = 0; q < 256; q++) {
      float tb = pb[q], tc = pc[q];
      pb[q] = rb; pc[q] = rc;
      rb += tb; rc += tc;
    }
    Sb[0] = 0.f; Sc[0] = 0.f;
    Sb[NB] = rb; Sc[NB] = rc;
  }
  __syncthreads();
  {
    float rb = pb[t], rc = pc[t];
    for (int c = t * 32; c < t * 32 + 32; c++) {
      rb += wbg[c]; rc += wcg[c];
      if (c + 1 < NB) { Sb[c + 1] = rb; Sc[c + 1] = rc; }
    }
  }
  __syncthreads();

  // ---- finalize: per-i scalars + LDS histogram of boundary buckets ----
  const float SbT = Sb[NB];
  for (int q = 0; q < NB / 256; q++) {
    int i = q * 256 + t;
    float s1i = s1[i];
    int c = ci[i];
    float q1 = __expf(0.2f * s1i), q2 = __expf(s1i);
    float l = q1 * (SbT - Sb[c]) + q2 * Sc[c];
    f1[i] = q1 / l;
    f2[i] = q2 / l;
    atomicAdd(&histL[c], 1);
  }
  __syncthreads();

  // ---- bucket scan: exclusive prefix of histL -> istart, cursor ----
  {
    const int lo = t * 33;
    const int hi = min(lo + 33, NB + 1);
    int s = 0;
    for (int b = lo; b < hi; b++) s += histL[b];
    ps[t] = s;
    __syncthreads();
    if (t == 0) {
      int r = 0;
      for (int q = 0; q < 256; q++) { int v = ps[q]; ps[q] = r; r += v; }
    }
    __syncthreads();
    int r = ps[t];
    for (int b = lo; b < hi; b++) { istart[b] = r; cursor[b] = r; r += histL[b]; }
    if (t == 255) istart[NB + 1] = r;
  }
}

// --------------------------- pass1: chunk totals (+ fused scatter) ----------
__global__ __launch_bounds__(256) void pass1_kernel(
    const uint16_t* __restrict__ h, const int* __restrict__ pi,
    const float* __restrict__ wbg, const float* __restrict__ wcg,
    float* __restrict__ Bct, float* __restrict__ Cct,
    const int* __restrict__ ci, int* __restrict__ cursor,
    int* __restrict__ ilist) {
  __shared__ int   pj[CH];
  __shared__ float wb[CH], wc[CH];
  const int t  = threadIdx.x;
  const int cb = blockIdx.x;
  const int k  = blockIdx.y;
  // fused scatter: first 32 flat blocks bucket-sort the i indices
  const int flat = k * 4 + cb;
  if (flat < 32) {
    const int i = flat * 256 + t;
    const int b = ci[i];
    const int pos = atomicAdd(&cursor[b], 1);
    ilist[pos] = i;
  }
  if (t < CH) {
    int g = k * CH + t;
    pj[t] = pi[g]; wb[t] = wbg[g]; wc[t] = wcg[g];
  }
  __syncthreads();
  const int n0 = cb * 1024 + t * 4;
  float b0 = 0.f, b1 = 0.f, b2 = 0.f, b3 = 0.f;
  float c0 = 0.f, c1 = 0.f, c2 = 0.f, c3 = 0.f;
#pragma unroll 8
  for (int c = 0; c < CH; c++) {
    uint2 hv = *(const uint2*)(h + (size_t)pj[c] * DF + n0);
    float h0 = bfu2f((uint16_t)hv.x), h1 = bfu2f((uint16_t)(hv.x >> 16));
    float h2 = bfu2f((uint16_t)hv.y), h3 = bfu2f((uint16_t)(hv.y >> 16));
    float vb = wb[c], vc = wc[c];
    b0 += vb * h0; b1 += vb * h1; b2 += vb * h2; b3 += vb * h3;
    c0 += vc * h0; c1 += vc * h1; c2 += vc * h2; c3 += vc * h3;
  }
  *(float4*)(Bct + (size_t)k * DF + n0) = make_float4(b0, b1, b2, b3);
  *(float4*)(Cct + (size_t)k * DF + n0) = make_float4(c0, c1, c2, c3);
}

// --------------------------- chunk offset scan (per column) -----------------
__global__ __launch_bounds__(256) void boff_kernel(
    const float* __restrict__ Bct, const float* __restrict__ Cct,
    float* __restrict__ Boff, float* __restrict__ Coff) {
  __shared__ float sB[4][64], sC[4][64];
  const int t   = threadIdx.x;
  const int cl  = t & 63;
  const int seg = t >> 6;                    // 0..3 (32 chunks each)
  const int col = blockIdx.x * 64 + cl;
  float sb = 0.f, sc = 0.f;
#pragma unroll 8
  for (int u = 0; u < NCH / 4; u++) {
    int kk = seg * (NCH / 4) + u;
    sb += Bct[(size_t)kk * DF + col];
    sc += Cct[(size_t)kk * DF + col];
  }
  sB[seg][cl] = sb; sC[seg][cl] = sc;
  __syncthreads();
  float rb = 0.f, rc = 0.f;
#pragma unroll
  for (int s = 0; s < 3; s++)
    if (s < seg) { rb += sB[s][cl]; rc += sC[s][cl]; }
#pragma unroll 4
  for (int u = 0; u < NCH / 4; u++) {
    int kk = seg * (NCH / 4) + u;
    Boff[(size_t)kk * DF + col] = rb;
    Coff[(size_t)kk * DF + col] = rc;
    rb += Bct[(size_t)kk * DF + col];
    rc += Cct[(size_t)kk * DF + col];
  }
  if (seg == 3) {
    Boff[(size_t)NCH * DF + col] = rb;      // = A_n
    Coff[(size_t)NCH * DF + col] = rc;
  }
}

// --------------------------- pass2: sweep + direct emission -----------------
__global__ __launch_bounds__(256) void pass2_kernel(
    const uint16_t* __restrict__ h, const int* __restrict__ pi,
    const float* __restrict__ wbg, const float* __restrict__ wcg,
    const float* __restrict__ Boff, const float* __restrict__ Coff,
    const int* __restrict__ istart, const int* __restrict__ ilist,
    const float* __restrict__ f1, const float* __restrict__ f2,
    float* __restrict__ out) {
  __shared__ int   pj[CH];
  __shared__ float wb[CH], wc[CH];
  __shared__ int   se[CH + 2];
  const int t  = threadIdx.x;
  const int cb = blockIdx.x;
  const int k  = blockIdx.y;
  if (t < CH) {
    int g = k * CH + t;
    pj[t] = pi[g]; wb[t] = wbg[g]; wc[t] = wcg[g];
  }
  if (t < CH + 2) se[t] = istart[k * CH + t];
  __syncthreads();
  const int n0 = cb * 1024 + t * 4;
  const float4 An = *(const float4*)(Boff + (size_t)NCH * DF + n0);
  const float4 Bo = *(const float4*)(Boff + (size_t)k * DF + n0);
  const float4 Co = *(const float4*)(Coff + (size_t)k * DF + n0);
  float b0 = Bo.x, b1 = Bo.y, b2 = Bo.z, b3 = Bo.w;
  float c0 = Co.x, c1 = Co.y, c2 = Co.z, c3 = Co.w;

  if (k == 0) {   // bucket 0: boundary before any j (c_i == 0)
    for (int idx = se[0]; idx < se[1]; idx++) {
      const int i = ilist[idx];
      const float fa = f1[i];
      *(float4*)(out + (size_t)i * DF + n0) =
          make_float4(fa * An.x, fa * An.y, fa * An.z, fa * An.w);
    }
  }
  for (int c = 0; c < CH; c++) {
    uint2 hv = *(const uint2*)(h + (size_t)pj[c] * DF + n0);
    float h0 = bfu2f((uint16_t)hv.x), h1 = bfu2f((uint16_t)(hv.x >> 16));
    float h2 = bfu2f((uint16_t)hv.y), h3 = bfu2f((uint16_t)(hv.y >> 16));
    float vb = wb[c], vc = wc[c];
    b0 += vb * h0; b1 += vb * h1; b2 += vb * h2; b3 += vb * h3;
    c0 += vc * h0; c1 += vc * h1; c2 += vc * h2; c3 += vc * h3;
    const int e0 = se[c + 1], e1 = se[c + 2];
    for (int idx = e0; idx < e1; idx++) {
      const int i = ilist[idx];
      const float fa = f1[i], fb = f2[i];
      *(float4*)(out + (size_t)i * DF + n0) = make_float4(
          fa * (An.x - b0) + fb * c0, fa * (An.y - b1) + fb * c1,
          fa * (An.z - b2) + fb * c2, fa * (An.w - b3) + fb * c3);
    }
  }
}

// ---------------------------------------------------------------------------
extern "C" void kernel_launch(void* const* d_in, const int* in_sizes, int n_in,
                              void* d_out, int out_size, void* d_ws, size_t ws_size,
                              hipStream_t stream) {
  const float* x = (const float*)d_in[0];   // [8192][4096] fp32
  const float* W = (const float*)d_in[1];   // [4096][4096] fp32
  const float* a = (const float*)d_in[2];   // [8192] fp32
  float* out = (float*)d_out;               // [8192][4096] fp32

  char* ws = (char*)d_ws;
  uint16_t* h = (uint16_t*)ws;                 // 64 MB
  char* sm = ws + 67108864;
  float* s1       = (float*)(sm);
  float* s2       = (float*)(sm + 65536);
  float* s2sorted = (float*)(sm + 131072);
  int*   pi       = (int*)  (sm + 196608);
  int*   ci       = (int*)  (sm + 262144);
  float* Sb       = (float*)(sm + 327680);     // NB+1 floats
  float* Sc       = (float*)(sm + 393216);
  float* wbg      = (float*)(sm + 458752);
  float* wcg      = (float*)(sm + 524288);
  float* f1       = (float*)(sm + 589824);
  float* f2       = (float*)(sm + 655360);
  int*   istart   = (int*)  (sm + 786432);     // NB+2 ints
  int*   cursor   = (int*)  (sm + 851968);     // NB+1 ints
  int*   ilist    = (int*)  (sm + 917504);     // NB ints
  float* Bct      = (float*)(sm + 1048576);    // NCH*DF*4 = 2 MB
  float* Cct      = (float*)(sm + 3145728);    // 2 MB
  float* Boff     = (float*)(sm + 5242880);    // (NCH+1)*DF*4 ~ 2.02 MB
  float* Coff     = (float*)(sm + 7602176);    // ~2.02 MB (ends sm+9.96MB)
  char* base2 = ws + 67108864 + 10485760;      // staging (dead after gemm)
  uint16_t* xb = (uint16_t*)base2;             // 64 MB
  uint16_t* Wb = (uint16_t*)(base2 + 67108864);// 32 MB  (total ws ~169 MB)

  // 1-2: cvt (cvt1 also zeroes s1/s2 for the gemm-epilogue atomics)
  cvt_f32_to_bf16<<<1024, 256, 0, stream>>>(x, xb, (NB * DF) / 4, s1, s2, NB);
  cvt_f32_to_bf16<<<1024, 256, 0, stream>>>(W, Wb, (DF * DF) / 4,
                                            nullptr, nullptr, 0);

  // 3: GEMM + fused s12
  gemm_nt_async<<<(NB / 256) * (DF / 256), 512, 0, stream>>>(
      xb, Wb, h, a, s1, s2);

  // 4: rank + count (4-way j-split)
  rankcount_kernel<<<NB / 64, 256, 0, stream>>>(s1, s2, pi, s2sorted, ci);

  // 5: scan + finalize + bucket_scan
  mega_kernel<<<1, 256, 0, stream>>>(s2sorted, Sb, Sc, wbg, wcg,
                                     s1, ci, f1, f2, istart, cursor);

  // 6: pass1 (+ fused scatter)
  pass1_kernel<<<dim3(DF / 1024, NCH), 256, 0, stream>>>(
      h, pi, wbg, wcg, Bct, Cct, ci, cursor, ilist);

  // 7: per-column chunk-offset scan
  boff_kernel<<<DF / 64, 256, 0, stream>>>(Bct, Cct, Boff, Coff);

  // 8: sweep + direct emission
  pass2_kernel<<<dim3(DF / 1024, NCH), 256, 0, stream>>>(
      h, pi, wbg, wcg, Boff, Coff, istart, ilist, f1, f2, out);
}